// Round 1
// baseline (3492.327 us; speedup 1.0000x reference)
//
#include <hip/hip_runtime.h>
#include <math.h>

#define Bn 32
#define Sn 512
#define Dn 768
#define Hn 8
#define DKn 96
#define Pn 3

// ---------------- block reduction helpers (blockDim == 256) ----------------
__device__ __forceinline__ float brsum(float v, float* red) {
    int t = threadIdx.x;
    red[t] = v; __syncthreads();
    #pragma unroll
    for (int o = 128; o > 0; o >>= 1) {
        if (t < o) red[t] += red[t + o];
        __syncthreads();
    }
    float r = red[0]; __syncthreads();
    return r;
}
__device__ __forceinline__ float brmax(float v, float* red) {
    int t = threadIdx.x;
    red[t] = v; __syncthreads();
    #pragma unroll
    for (int o = 128; o > 0; o >>= 1) {
        if (t < o) red[t] = fmaxf(red[t], red[t + o]);
        __syncthreads();
    }
    float r = red[0]; __syncthreads();
    return r;
}

// ---------------- LayerNorm (torch-style: unbiased var, eps added to std) ----------------
__global__ __launch_bounds__(256) void ln_kernel(const float* __restrict__ in,
                                                 const float* __restrict__ ga,
                                                 const float* __restrict__ gb,
                                                 float* __restrict__ out) {
    __shared__ float red[256];
    long row = blockIdx.x;  // B*S rows
    const float* x = in + row * Dn;
    float* y = out + row * Dn;
    int t = threadIdx.x;
    float v0 = x[t], v1 = x[t + 256], v2 = x[t + 512];
    float mean = brsum(v0 + v1 + v2, red) / (float)Dn;
    float d0 = v0 - mean, d1 = v1 - mean, d2 = v2 - mean;
    float ss = brsum(d0 * d0 + d1 * d1 + d2 * d2, red);
    float inv = 1.0f / (sqrtf(ss / (float)(Dn - 1)) + 1e-6f);
    y[t]       = ga[t]       * d0 * inv + gb[t];
    y[t + 256] = ga[t + 256] * d1 * inv + gb[t + 256];
    y[t + 512] = ga[t + 512] * d2 * inv + gb[t + 512];
}

// ---------------- Tiled SGEMM: C = alpha * A @ op(B) [+bias] [mask] [/denom + relu] -------
// BT=true : B is [N,K] row-major (compute A @ B^T)
// BT=false: B is [K,N] row-major (compute A @ B)
// All of M, N divisible by 128; K divisible by 16. Batched via blockIdx.z.
#define BMt 128
#define BNt 128
#define BKt 16
#define PADT 132

template <bool BT>
__global__ __launch_bounds__(256) void sgemm(const float* __restrict__ A,
                                             const float* __restrict__ Bm,
                                             float* __restrict__ C,
                                             int M, int N, int K,
                                             int lda, int ldb, int ldc,
                                             long sA, long sB, long sC,
                                             float alpha,
                                             const float* __restrict__ bias,
                                             const int* __restrict__ mask,
                                             const float* __restrict__ denom) {
    __shared__ float As[BKt][PADT];
    __shared__ float Bs[BKt][PADT];
    int bz = blockIdx.z;
    const float* Ab = A + (long)bz * sA;
    const float* Bb = Bm + (long)bz * sB;
    float* Cb = C + (long)bz * sC;
    int n0 = blockIdx.x * BNt;
    int m0 = blockIdx.y * BMt;
    int tid = threadIdx.x;
    int tx = tid & 15, ty = tid >> 4;

    float acc[8][8];
    #pragma unroll
    for (int i = 0; i < 8; i++)
        #pragma unroll
        for (int j = 0; j < 8; j++) acc[i][j] = 0.0f;

    for (int k0 = 0; k0 < K; k0 += BKt) {
        // stage A tile: 128 rows x 16 k, store k-major (transposed)
        #pragma unroll
        for (int p = 0; p < 2; ++p) {
            int slot = tid + p * 256;     // 0..511
            int row = slot >> 2;
            int kq = slot & 3;
            const float4 v = *reinterpret_cast<const float4*>(Ab + (long)(m0 + row) * lda + k0 + kq * 4);
            As[kq * 4 + 0][row] = v.x;
            As[kq * 4 + 1][row] = v.y;
            As[kq * 4 + 2][row] = v.z;
            As[kq * 4 + 3][row] = v.w;
        }
        if (BT) {
            #pragma unroll
            for (int p = 0; p < 2; ++p) {
                int slot = tid + p * 256;
                int row = slot >> 2;
                int kq = slot & 3;
                const float4 v = *reinterpret_cast<const float4*>(Bb + (long)(n0 + row) * ldb + k0 + kq * 4);
                Bs[kq * 4 + 0][row] = v.x;
                Bs[kq * 4 + 1][row] = v.y;
                Bs[kq * 4 + 2][row] = v.z;
                Bs[kq * 4 + 3][row] = v.w;
            }
        } else {
            #pragma unroll
            for (int p = 0; p < 2; ++p) {
                int slot = tid + p * 256;
                int kk = slot >> 5;       // 0..15
                int c4 = slot & 31;       // 0..31
                const float4 v = *reinterpret_cast<const float4*>(Bb + (long)(k0 + kk) * ldb + n0 + c4 * 4);
                *reinterpret_cast<float4*>(&Bs[kk][c4 * 4]) = v;
            }
        }
        __syncthreads();
        #pragma unroll
        for (int kk = 0; kk < BKt; ++kk) {
            float4 a0 = *reinterpret_cast<const float4*>(&As[kk][ty * 4]);
            float4 a1 = *reinterpret_cast<const float4*>(&As[kk][64 + ty * 4]);
            float4 b0 = *reinterpret_cast<const float4*>(&Bs[kk][tx * 4]);
            float4 b1 = *reinterpret_cast<const float4*>(&Bs[kk][64 + tx * 4]);
            float a[8] = {a0.x, a0.y, a0.z, a0.w, a1.x, a1.y, a1.z, a1.w};
            float b[8] = {b0.x, b0.y, b0.z, b0.w, b1.x, b1.y, b1.z, b1.w};
            #pragma unroll
            for (int i = 0; i < 8; i++)
                #pragma unroll
                for (int j = 0; j < 8; j++) acc[i][j] = fmaf(a[i], b[j], acc[i][j]);
        }
        __syncthreads();
    }
    // epilogue
    #pragma unroll
    for (int i = 0; i < 8; i++) {
        int m = m0 + ((i < 4) ? (ty * 4 + i) : (64 + ty * 4 + (i - 4)));
        float dinv = 1.0f;
        if (denom) dinv = 1.0f / denom[(long)bz * M + m];
        float vv[8];
        #pragma unroll
        for (int j = 0; j < 8; j++) {
            int n = n0 + ((j < 4) ? (tx * 4 + j) : (64 + tx * 4 + (j - 4)));
            float v = acc[i][j] * alpha;
            if (bias) v += bias[n];
            if (mask && mask[(long)bz * N + n] == 0) v = -1e9f;
            if (denom) v = fmaxf(v * dinv, 0.0f);
            vv[j] = v;
        }
        float* orow = Cb + (long)m * ldc;
        *reinterpret_cast<float4*>(orow + n0 + tx * 4)      = make_float4(vv[0], vv[1], vv[2], vv[3]);
        *reinterpret_cast<float4*>(orow + n0 + 64 + tx * 4) = make_float4(vv[4], vv[5], vv[6], vv[7]);
    }
}

// ---------------- softmax over score rows, accumulate mean over heads into adj ------------
// grid = B*S blocks; at finalize: set diag=1, scale row by mask, emit denom = rowsum + 1
__global__ __launch_bounds__(256) void softmax_acc(const float* __restrict__ scores,
                                                   float* __restrict__ adj,
                                                   float* __restrict__ denomv,
                                                   const int* __restrict__ mask,
                                                   int init, int finalize) {
    __shared__ float red[256];
    long bid = blockIdx.x;  // b*S + q
    int t = threadIdx.x;
    const float* row = scores + bid * Sn;
    float s0 = row[t], s1 = row[t + 256];
    float mx = brmax(fmaxf(s0, s1), red);
    float e0 = expf(s0 - mx), e1 = expf(s1 - mx);
    float sm = brsum(e0 + e1, red);
    float c0 = e0 / sm * 0.125f, c1 = e1 / sm * 0.125f;
    float* arow = adj + bid * Sn;
    float a0 = init ? c0 : (arow[t] + c0);
    float a1 = init ? c1 : (arow[t + 256] + c1);
    if (finalize) {
        int b = (int)(bid >> 9), q = (int)(bid & 511);
        if (t == q) a0 = 1.0f;
        if (t + 256 == q) a1 = 1.0f;
        float mrow = (float)mask[b * Sn + q];
        a0 *= mrow; a1 *= mrow;
        float dsum = brsum(a0 + a1, red);
        if (t == 0) denomv[bid] = dsum + 1.0f;
    }
    arow[t] = a0;
    arow[t + 256] = a1;
}

// ---------------- zero helper ----------------
__global__ void zero_kernel(float* p, int n) {
    int i = blockIdx.x * 256 + threadIdx.x;
    if (i < n) p[i] = 0.0f;
}

// ---------------- sequence reduction: outv[b,d] += sum_s H[b,s,d] (* weight) ------------
// grid = (Dn/256, 4 s-chunks, B); block 256
__global__ __launch_bounds__(256) void reduce_seq(const float* __restrict__ Hb,
                                                  const float* __restrict__ aw,
                                                  float* __restrict__ outv) {
    int b = blockIdx.z;
    int d = blockIdx.x * 256 + threadIdx.x;
    int s0 = blockIdx.y * 128;
    const float* base = Hb + ((long)b * Sn + s0) * Dn + d;
    float sum = 0.0f;
    if (aw) {
        const float* w = aw + (long)b * Sn + s0;
        for (int s = 0; s < 128; s++) sum += base[(long)s * Dn] * w[s];
    } else {
        for (int s = 0; s < 128; s++) sum += base[(long)s * Dn];
    }
    atomicAdd(&outv[(long)b * Dn + d], sum);
}

// ---------------- final: asp_wn, proj x2, logits, label copy ----------------
__global__ __launch_bounds__(256) void final_kernel(const float* __restrict__ ofp,
                                                    const float* __restrict__ ofc_raw,
                                                    const float* __restrict__ aspect,
                                                    const float* __restrict__ pooled,
                                                    const float* __restrict__ fpdW,
                                                    const float* __restrict__ fpdb,
                                                    const float* __restrict__ fcdW,
                                                    const float* __restrict__ fcdb,
                                                    float* __restrict__ out) {
    __shared__ float red[256];
    __shared__ float fp[Dn], fc[Dn], fy[Dn];
    int b = blockIdx.x, t = threadIdx.x;
    float awv = aspect[(long)b * Sn + t] + aspect[(long)b * Sn + t + 256];
    float asp_wn = brsum(awv, red);
    for (int i = t; i < Dn; i += 256) {
        fp[i] = ofp[(long)b * Dn + i];
        fc[i] = ofc_raw[(long)b * Dn + i] / asp_wn;
    }
    __syncthreads();
    float p0 = 0.0f, p1 = 0.0f;
    for (int i = t; i < Dn; i += 256) { p0 += fc[i] * fc[i]; p1 += fp[i] * fc[i]; }
    float dfc2 = brsum(p0, red);
    float dfpfc = brsum(p1, red);
    float bmo = sqrtf(dfc2);
    float coef = dfpfc / bmo;
    float bden = fmaxf(bmo, 1e-12f);
    // t = fp - fp_x, store in fy for now
    float q0 = 0.0f, q1 = 0.0f;
    for (int i = t; i < Dn; i += 256) {
        float tv = fp[i] - coef * fc[i] / bden;
        fy[i] = tv;
        q0 += tv * tv;
        q1 += fp[i] * tv;
    }
    float dt2 = brsum(q0, red);   // includes syncthreads: fy writes visible afterwards
    float dfpt = brsum(q1, red);
    float tmo = sqrtf(dt2);
    float coef2 = dfpt / tmo;
    float tden = fmaxf(tmo, 1e-12f);
    for (int i = t; i < Dn; i += 256) fy[i] = coef2 * fy[i] / tden;
    __syncthreads();
    // fp_y out
    for (int i = t; i < Dn; i += 256) out[2 * Bn * Pn + (long)b * Dn + i] = fy[i];
    // label_embedding out
    for (int i = t; i < Dn; i += 256)
        out[2 * Bn * Pn + Bn * Dn + (long)b * Dn + i] = pooled[(long)b * Dn + i];
    // logits
    for (int j = 0; j < Pn; j++) {
        float lp = 0.0f, lc = 0.0f;
        for (int i = t; i < Dn; i += 256) {
            lp += fy[i] * fpdW[(long)j * Dn + i];
            lc += fc[i] * fcdW[(long)j * Dn + i];
        }
        float rp = brsum(lp, red);
        float rc = brsum(lc, red);
        if (t == 0) {
            out[(long)b * Pn + j] = rp + fpdb[j];
            out[Bn * Pn + (long)b * Pn + j] = rc + fcdb[j];
        }
    }
}

// ---------------- host orchestration ----------------
extern "C" void kernel_launch(void* const* d_in, const int* in_sizes, int n_in,
                              void* d_out, int out_size, void* d_ws, size_t ws_size,
                              hipStream_t stream) {
    const float* seq     = (const float*)d_in[0];
    const float* pooled  = (const float*)d_in[1];
    const int*   src_msk = (const int*)d_in[2];
    const float* aspect  = (const float*)d_in[3];
    const float* ln_a    = (const float*)d_in[4];
    const float* ln_b    = (const float*)d_in[5];
    float* out = (float*)d_out;

    const long NTD = (long)Bn * Sn * Dn;       // 12,582,912
    const long NSS = (long)Bn * Sn * Sn;       // 8,388,608
    float* ws = (float*)d_ws;
    float* x      = ws;
    float* B1     = x + NTD;
    float* B2     = B1 + NTD;
    float* scores = B2 + NTD;
    float* adj    = scores + NSS;
    float* denom  = adj + NSS;
    float* ofp    = denom + (long)Bn * Sn;
    float* ofc    = ofp + (long)Bn * Dn;

    // 1. LayerNorm
    ln_kernel<<<dim3(Bn * Sn), dim3(256), 0, stream>>>(seq, ln_a, ln_b, x);

    const float inv_sqrt_dk = 1.0f / sqrtf((float)DKn);

    for (int br = 0; br < 2; ++br) {
        const float* Wq = (const float*)d_in[6 + br * 8 + 0];
        const float* bq = (const float*)d_in[6 + br * 8 + 1];
        const float* Wk = (const float*)d_in[6 + br * 8 + 2];
        const float* bk = (const float*)d_in[6 + br * 8 + 3];
        const float* W0 = (const float*)d_in[6 + br * 8 + 4];
        const float* b0 = (const float*)d_in[6 + br * 8 + 5];
        const float* W1 = (const float*)d_in[6 + br * 8 + 6];
        const float* b1 = (const float*)d_in[6 + br * 8 + 7];
        float* outv = (br == 0) ? ofp : ofc;

        // Q = x @ Wq^T + bq ; K = x @ Wk^T + bk
        sgemm<true><<<dim3(6, 128, 1), dim3(256), 0, stream>>>(
            x, Wq, B1, Bn * Sn, Dn, Dn, Dn, Dn, Dn, 0, 0, 0, 1.0f, bq, nullptr, nullptr);
        sgemm<true><<<dim3(6, 128, 1), dim3(256), 0, stream>>>(
            x, Wk, B2, Bn * Sn, Dn, Dn, Dn, Dn, Dn, 0, 0, 0, 1.0f, bk, nullptr, nullptr);

        // adj = mean_h softmax(mask(Q_h K_h^T / sqrt(dk)))  (+diag/rowmask/denom at h==7)
        for (int h = 0; h < Hn; ++h) {
            sgemm<true><<<dim3(4, 4, Bn), dim3(256), 0, stream>>>(
                B1 + h * DKn, B2 + h * DKn, scores, Sn, Sn, DKn,
                Dn, Dn, Sn, (long)Sn * Dn, (long)Sn * Dn, (long)Sn * Sn,
                inv_sqrt_dk, nullptr, src_msk, nullptr);
            softmax_acc<<<dim3(Bn * Sn), dim3(256), 0, stream>>>(
                scores, adj, denom, src_msk, (h == 0) ? 1 : 0, (h == Hn - 1) ? 1 : 0);
        }

        // GCN layer 1: H1 = relu((adj @ (x @ W0^T) + b0)/denom)
        sgemm<true><<<dim3(6, 128, 1), dim3(256), 0, stream>>>(
            x, W0, B1, Bn * Sn, Dn, Dn, Dn, Dn, Dn, 0, 0, 0, 1.0f, nullptr, nullptr, nullptr);
        sgemm<false><<<dim3(6, 4, Bn), dim3(256), 0, stream>>>(
            adj, B1, B2, Sn, Dn, Sn, Sn, Dn, Dn,
            (long)Sn * Sn, (long)Sn * Dn, (long)Sn * Dn, 1.0f, b0, nullptr, denom);

        // GCN layer 2: H2 = relu((adj @ (H1 @ W1^T) + b1)/denom)
        sgemm<true><<<dim3(6, 128, 1), dim3(256), 0, stream>>>(
            B2, W1, B1, Bn * Sn, Dn, Dn, Dn, Dn, Dn, 0, 0, 0, 1.0f, nullptr, nullptr, nullptr);
        sgemm<false><<<dim3(6, 4, Bn), dim3(256), 0, stream>>>(
            adj, B1, B2, Sn, Dn, Sn, Sn, Dn, Dn,
            (long)Sn * Sn, (long)Sn * Dn, (long)Sn * Dn, 1.0f, b1, nullptr, denom);

        // reduce over sequence
        zero_kernel<<<dim3((Bn * Dn + 255) / 256), dim3(256), 0, stream>>>(outv, Bn * Dn);
        reduce_seq<<<dim3(3, 4, Bn), dim3(256), 0, stream>>>(
            B2, (br == 1) ? aspect : nullptr, outv);
    }

    final_kernel<<<dim3(Bn), dim3(256), 0, stream>>>(
        ofp, ofc, aspect, pooled,
        (const float*)d_in[22], (const float*)d_in[23],
        (const float*)d_in[24], (const float*)d_in[25], out);
}

// Round 2
// 660.642 us; speedup vs baseline: 5.2863x; 5.2863x over previous
//
#include <hip/hip_runtime.h>
#include <math.h>
#include <stdint.h>

#define Bn 32
#define Sn 512
#define Dn 768
#define Hn 8
#define DKn 96
#define Pn 3

typedef __bf16 bf16_t;
typedef bf16_t bf16x8 __attribute__((ext_vector_type(8)));
typedef float f32x4 __attribute__((ext_vector_type(4)));

__device__ __forceinline__ bf16_t f2bf(float f) { return (bf16_t)f; }

__device__ __forceinline__ void gload16(const void* g, void* l) {
    __builtin_amdgcn_global_load_lds((const __attribute__((address_space(1))) void*)g,
                                     (__attribute__((address_space(3))) void*)l, 16, 0, 0);
}

// ---------------- block reduction helpers (blockDim == 256) ----------------
__device__ __forceinline__ float brsum(float v, float* red) {
    int t = threadIdx.x;
    red[t] = v; __syncthreads();
    #pragma unroll
    for (int o = 128; o > 0; o >>= 1) {
        if (t < o) red[t] += red[t + o];
        __syncthreads();
    }
    float r = red[0]; __syncthreads();
    return r;
}

// ---------------- LayerNorm -> bf16 (torch-style: unbiased var, eps on std) -------------
__global__ __launch_bounds__(256) void ln_kernel(const float* __restrict__ in,
                                                 const float* __restrict__ ga,
                                                 const float* __restrict__ gb,
                                                 bf16_t* __restrict__ out) {
    __shared__ float red[256];
    long row = blockIdx.x;
    const float* x = in + row * Dn;
    bf16_t* y = out + row * Dn;
    int t = threadIdx.x;
    float v0 = x[t], v1 = x[t + 256], v2 = x[t + 512];
    float mean = brsum(v0 + v1 + v2, red) / (float)Dn;
    float d0 = v0 - mean, d1 = v1 - mean, d2 = v2 - mean;
    float ss = brsum(d0 * d0 + d1 * d1 + d2 * d2, red);
    float inv = 1.0f / (sqrtf(ss / (float)(Dn - 1)) + 1e-6f);
    y[t]       = f2bf(ga[t]       * d0 * inv + gb[t]);
    y[t + 256] = f2bf(ga[t + 256] * d1 * inv + gb[t + 256]);
    y[t + 512] = f2bf(ga[t + 512] * d2 * inv + gb[t + 512]);
}

// ---------------- fp32 -> bf16 weight conversion (4 matrices of Dn x Dn) -----------------
__global__ __launch_bounds__(256) void cvt4(const float* __restrict__ s0,
                                            const float* __restrict__ s1,
                                            const float* __restrict__ s2,
                                            const float* __restrict__ s3,
                                            bf16_t* __restrict__ dst) {
    const float* s = (blockIdx.y == 0) ? s0 : (blockIdx.y == 1) ? s1 : (blockIdx.y == 2) ? s2 : s3;
    long i = (long)blockIdx.x * 1024 + threadIdx.x * 4;
    float4 v = *reinterpret_cast<const float4*>(s + i);
    bf16_t* d = dst + (long)blockIdx.y * Dn * Dn + i;
    d[0] = f2bf(v.x); d[1] = f2bf(v.y); d[2] = f2bf(v.z); d[3] = f2bf(v.w);
}

__global__ void zero_kernel(float* p, int n) {
    int i = blockIdx.x * 256 + threadIdx.x;
    if (i < n) p[i] = 0.0f;
}

// ---------------- bf16 MFMA NT GEMM: C = alpha * A @ B^T (+epilogues) --------------------
// A [M,K] row-major lda, B [N,K] row-major ldb; both k-contiguous.
// 128x128 tile, 4 waves (2x2 of 64x64), BK=32, global_load_lds staging.
// EPI 0: C=bf16( alpha*acc + bias? )
// EPI 1: C=bf16( relu((acc + bias[n]) / denom[zb*Sn+m]) )
// EPI 2: no C; atomicAdd outv[zb*Dn+n] += sum_m w(m)*relu((acc+bias[n])/denom[m])
template <int EPI>
__global__ __launch_bounds__(256) void gemm_bt(
    const bf16_t* __restrict__ Ag, const bf16_t* __restrict__ Bg,
    bf16_t* __restrict__ Cg, float* __restrict__ outv,
    int lda, int ldb, int ldc, int K,
    long sA1, long sA2, long sB1, long sB2, long sC1, long sC2, int lgG,
    float alpha,
    const float* __restrict__ bias,
    const float* __restrict__ denom,
    const float* __restrict__ aspw) {
    __shared__ __align__(16) bf16_t As[128 * 32];
    __shared__ __align__(16) bf16_t Bs[128 * 32];

    int z = blockIdx.z;
    int zb = z >> lgG;
    int zg = z - (zb << lgG);
    const bf16_t* A = Ag + zb * sA1 + zg * sA2;
    const bf16_t* B = Bg + zb * sB1 + zg * sB2;

    int n0 = blockIdx.x * 128;
    int m0 = blockIdx.y * 128;
    int tid = threadIdx.x;
    int lane = tid & 63, wv = tid >> 6;
    int wm = wv >> 1, wn = wv & 1;

    // staging: chunk c = r*4+wv covers rows c*16..c*16+15 (1024B contiguous LDS per wave)
    int sub = lane >> 2;           // row within 16-row chunk
    int kcol = (lane & 3) * 8;     // k element offset (16B granule)
    const bf16_t* pA0 = A + (size_t)(m0 + wv * 16 + sub) * lda + kcol;
    const bf16_t* pA1 = pA0 + (size_t)64 * lda;
    const bf16_t* pB0 = B + (size_t)(n0 + wv * 16 + sub) * ldb + kcol;
    const bf16_t* pB1 = pB0 + (size_t)64 * ldb;
    bf16_t* lA0 = As + wv * 512 + lane * 8;
    bf16_t* lA1 = As + (4 + wv) * 512 + lane * 8;
    bf16_t* lB0 = Bs + wv * 512 + lane * 8;
    bf16_t* lB1 = Bs + (4 + wv) * 512 + lane * 8;

    f32x4 acc[4][4];
    #pragma unroll
    for (int i = 0; i < 4; i++)
        #pragma unroll
        for (int j = 0; j < 4; j++) acc[i][j] = (f32x4){0.f, 0.f, 0.f, 0.f};

    const bf16_t* ar = As + (wm * 64 + (lane & 15)) * 32 + (lane >> 4) * 8;
    const bf16_t* br = Bs + (wn * 64 + (lane & 15)) * 32 + (lane >> 4) * 8;

    for (int k0 = 0; k0 < K; k0 += 32) {
        gload16(pA0 + k0, lA0);
        gload16(pA1 + k0, lA1);
        gload16(pB0 + k0, lB0);
        gload16(pB1 + k0, lB1);
        __syncthreads();
        bf16x8 a[4], b[4];
        #pragma unroll
        for (int i = 0; i < 4; i++) a[i] = *(const bf16x8*)(ar + i * 16 * 32);
        #pragma unroll
        for (int j = 0; j < 4; j++) b[j] = *(const bf16x8*)(br + j * 16 * 32);
        #pragma unroll
        for (int i = 0; i < 4; i++)
            #pragma unroll
            for (int j = 0; j < 4; j++)
                acc[i][j] = __builtin_amdgcn_mfma_f32_16x16x32_bf16(a[i], b[j], acc[i][j], 0, 0, 0);
        __syncthreads();
    }

    int nb = n0 + wn * 64 + (lane & 15);
    int mbase = m0 + wm * 64 + (lane >> 4) * 4;

    if (EPI == 0) {
        bf16_t* Cz = Cg + zb * sC1 + zg * sC2;
        #pragma unroll
        for (int i = 0; i < 4; i++) {
            #pragma unroll
            for (int r = 0; r < 4; r++) {
                long m = mbase + i * 16 + r;
                bf16_t* crow = Cz + m * (long)ldc;
                #pragma unroll
                for (int j = 0; j < 4; j++) {
                    float v = acc[i][j][r] * alpha;
                    if (bias) v += bias[nb + j * 16];
                    crow[nb + j * 16] = f2bf(v);
                }
            }
        }
    } else if (EPI == 1) {
        bf16_t* Cz = Cg + zb * sC1 + zg * sC2;
        const float* dz = denom + (long)zb * Sn;
        #pragma unroll
        for (int i = 0; i < 4; i++) {
            #pragma unroll
            for (int r = 0; r < 4; r++) {
                int m = mbase + i * 16 + r;
                float dinv = 1.0f / dz[m];
                bf16_t* crow = Cz + (long)m * ldc;
                #pragma unroll
                for (int j = 0; j < 4; j++) {
                    float v = fmaxf((acc[i][j][r] + bias[nb + j * 16]) * dinv, 0.0f);
                    crow[nb + j * 16] = f2bf(v);
                }
            }
        }
    } else {  // EPI == 2
        const float* dz = denom + (long)zb * Sn;
        float csum[4] = {0.f, 0.f, 0.f, 0.f};
        #pragma unroll
        for (int i = 0; i < 4; i++) {
            #pragma unroll
            for (int r = 0; r < 4; r++) {
                int m = mbase + i * 16 + r;
                float dinv = 1.0f / dz[m];
                float w = aspw ? aspw[(long)zb * Sn + m] : 1.0f;
                #pragma unroll
                for (int j = 0; j < 4; j++) {
                    float v = fmaxf((acc[i][j][r] + bias[nb + j * 16]) * dinv, 0.0f);
                    csum[j] += v * w;
                }
            }
        }
        #pragma unroll
        for (int j = 0; j < 4; j++) {
            float s = csum[j];
            s += __shfl_xor(s, 16);
            s += __shfl_xor(s, 32);
            if (lane < 16) atomicAdd(&outv[(long)zb * Dn + nb + j * 16], s);
        }
    }
}

// ---------------- softmax over G heads, accumulate mean into adj -------------------------
// one wave per (b,q) row; scores layout [b][g][q][k] bf16 (z = b*G+g contiguous)
__global__ __launch_bounds__(256) void softmax_multi(
    const bf16_t* __restrict__ SC, float* __restrict__ adjf,
    bf16_t* __restrict__ adjb, float* __restrict__ denomv,
    const int* __restrict__ mask, int G, int init, int fin) {
    int wv = threadIdx.x >> 6, lane = threadIdx.x & 63;
    long rowid = (long)blockIdx.x * 4 + wv;  // b*Sn + q
    int b = (int)(rowid >> 9), q = (int)(rowid & 511);
    const int* mrow = mask + (long)b * Sn;

    bool mk[8];
    #pragma unroll
    for (int e = 0; e < 8; e++) mk[e] = (mrow[lane * 8 + e] != 0);

    float racc[8];
    if (init) {
        #pragma unroll
        for (int e = 0; e < 8; e++) racc[e] = 0.0f;
    } else {
        const float* ap = adjf + rowid * Sn + lane * 8;
        float4 r0 = *reinterpret_cast<const float4*>(ap);
        float4 r1 = *reinterpret_cast<const float4*>(ap + 4);
        racc[0] = r0.x; racc[1] = r0.y; racc[2] = r0.z; racc[3] = r0.w;
        racc[4] = r1.x; racc[5] = r1.y; racc[6] = r1.z; racc[7] = r1.w;
    }

    for (int g = 0; g < G; ++g) {
        const bf16_t* srow = SC + ((long)(b * G + g) * Sn + q) * Sn + lane * 8;
        bf16x8 sv = *(const bf16x8*)srow;
        float s[8];
        #pragma unroll
        for (int e = 0; e < 8; e++) s[e] = mk[e] ? (float)sv[e] : -1e9f;
        float mx = s[0];
        #pragma unroll
        for (int e = 1; e < 8; e++) mx = fmaxf(mx, s[e]);
        #pragma unroll
        for (int o = 1; o < 64; o <<= 1) mx = fmaxf(mx, __shfl_xor(mx, o));
        float es[8], sum = 0.0f;
        #pragma unroll
        for (int e = 0; e < 8; e++) { es[e] = __expf(s[e] - mx); sum += es[e]; }
        #pragma unroll
        for (int o = 1; o < 64; o <<= 1) sum += __shfl_xor(sum, o);
        float inv = 0.125f / sum;
        #pragma unroll
        for (int e = 0; e < 8; e++) racc[e] += es[e] * inv;
    }

    if (fin) {
        #pragma unroll
        for (int e = 0; e < 8; e++) racc[e] = (lane * 8 + e == q) ? 1.0f : racc[e];
        float rm = (float)mrow[q];  // row mask = mask[b,q]
        float rs = 0.0f;
        #pragma unroll
        for (int e = 0; e < 8; e++) { racc[e] *= rm; rs += racc[e]; }
        #pragma unroll
        for (int o = 1; o < 64; o <<= 1) rs += __shfl_xor(rs, o);
        if (lane == 0) denomv[rowid] = rs + 1.0f;
        bf16x8 o8;
        #pragma unroll
        for (int e = 0; e < 8; e++) o8[e] = f2bf(racc[e]);
        *(bf16x8*)(adjb + rowid * Sn + lane * 8) = o8;
    } else {
        float* ap = adjf + rowid * Sn + lane * 8;
        *reinterpret_cast<float4*>(ap) = make_float4(racc[0], racc[1], racc[2], racc[3]);
        *reinterpret_cast<float4*>(ap + 4) = make_float4(racc[4], racc[5], racc[6], racc[7]);
    }
}

// ---------------- final: asp_wn, proj x2, logits, label copy (fp32) ----------------------
__global__ __launch_bounds__(256) void final_kernel(const float* __restrict__ ofp,
                                                    const float* __restrict__ ofc_raw,
                                                    const float* __restrict__ aspect,
                                                    const float* __restrict__ pooled,
                                                    const float* __restrict__ fpdW,
                                                    const float* __restrict__ fpdb,
                                                    const float* __restrict__ fcdW,
                                                    const float* __restrict__ fcdb,
                                                    float* __restrict__ out) {
    __shared__ float red[256];
    __shared__ float fp[Dn], fc[Dn], fy[Dn];
    int b = blockIdx.x, t = threadIdx.x;
    float awv = aspect[(long)b * Sn + t] + aspect[(long)b * Sn + t + 256];
    float asp_wn = brsum(awv, red);
    for (int i = t; i < Dn; i += 256) {
        fp[i] = ofp[(long)b * Dn + i];
        fc[i] = ofc_raw[(long)b * Dn + i] / asp_wn;
    }
    __syncthreads();
    float p0 = 0.0f, p1 = 0.0f;
    for (int i = t; i < Dn; i += 256) { p0 += fc[i] * fc[i]; p1 += fp[i] * fc[i]; }
    float dfc2 = brsum(p0, red);
    float dfpfc = brsum(p1, red);
    float bmo = sqrtf(dfc2);
    float coef = dfpfc / bmo;
    float bden = fmaxf(bmo, 1e-12f);
    float q0 = 0.0f, q1 = 0.0f;
    for (int i = t; i < Dn; i += 256) {
        float tv = fp[i] - coef * fc[i] / bden;
        fy[i] = tv;
        q0 += tv * tv;
        q1 += fp[i] * tv;
    }
    float dt2 = brsum(q0, red);
    float dfpt = brsum(q1, red);
    float tmo = sqrtf(dt2);
    float coef2 = dfpt / tmo;
    float tden = fmaxf(tmo, 1e-12f);
    for (int i = t; i < Dn; i += 256) fy[i] = coef2 * fy[i] / tden;
    __syncthreads();
    for (int i = t; i < Dn; i += 256) out[2 * Bn * Pn + (long)b * Dn + i] = fy[i];
    for (int i = t; i < Dn; i += 256)
        out[2 * Bn * Pn + Bn * Dn + (long)b * Dn + i] = pooled[(long)b * Dn + i];
    for (int j = 0; j < Pn; j++) {
        float lp = 0.0f, lc = 0.0f;
        for (int i = t; i < Dn; i += 256) {
            lp += fy[i] * fpdW[(long)j * Dn + i];
            lc += fc[i] * fcdW[(long)j * Dn + i];
        }
        float rp = brsum(lp, red);
        float rc = brsum(lc, red);
        if (t == 0) {
            out[(long)b * Pn + j] = rp + fpdb[j];
            out[Bn * Pn + (long)b * Pn + j] = rc + fcdb[j];
        }
    }
}

// ---------------- host orchestration ----------------
extern "C" void kernel_launch(void* const* d_in, const int* in_sizes, int n_in,
                              void* d_out, int out_size, void* d_ws, size_t ws_size,
                              hipStream_t stream) {
    const float* seq     = (const float*)d_in[0];
    const float* pooled  = (const float*)d_in[1];
    const int*   src_msk = (const int*)d_in[2];
    const float* aspect  = (const float*)d_in[3];
    const float* ln_a    = (const float*)d_in[4];
    const float* ln_b    = (const float*)d_in[5];
    float* out = (float*)d_out;

    const long NTD = (long)Bn * Sn * Dn;   // 12,582,912
    const long NSS = (long)Bn * Sn * Sn;   // 8,388,608
    const long DD  = (long)Dn * Dn;        // 589,824

    char* w = (char*)d_ws;
    bf16_t* xbf  = (bf16_t*)w;
    bf16_t* Qb   = xbf + NTD;   // later reused as H1
    bf16_t* Kb   = Qb + NTD;
    bf16_t* adjb = Kb + NTD;
    float*  denom = (float*)(adjb + NSS);
    float*  ofp   = denom + (long)Bn * Sn;
    float*  ofc   = ofp + (long)Bn * Dn;
    bf16_t* Wb    = (bf16_t*)(ofc + (long)Bn * Dn);
    bf16_t* SC    = Wb + 4 * DD;          // scores region; later aliased as XT
    bf16_t* XT    = SC;

    size_t base_bytes = (size_t)((char*)SC - w);
    int G;
    float* adjf = nullptr;
    if (ws_size >= base_bytes + (size_t)8 * NSS * sizeof(bf16_t)) {
        G = 8;
    } else {
        G = 2;
        adjf = (float*)(SC + 2 * NSS);
    }
    int lgG = (G == 8) ? 3 : 1;
    int ngrp = Hn / G;
    const float sal = 1.0f / sqrtf((float)DKn);

    ln_kernel<<<dim3(Bn * Sn), dim3(256), 0, stream>>>(seq, ln_a, ln_b, xbf);
    zero_kernel<<<dim3((2 * Bn * Dn + 255) / 256), dim3(256), 0, stream>>>(ofp, 2 * Bn * Dn);

    for (int br = 0; br < 2; ++br) {
        const float* Wq = (const float*)d_in[6 + br * 8 + 0];
        const float* bq = (const float*)d_in[6 + br * 8 + 1];
        const float* Wk = (const float*)d_in[6 + br * 8 + 2];
        const float* bk = (const float*)d_in[6 + br * 8 + 3];
        const float* W0 = (const float*)d_in[6 + br * 8 + 4];
        const float* b0 = (const float*)d_in[6 + br * 8 + 5];
        const float* W1 = (const float*)d_in[6 + br * 8 + 6];
        const float* b1 = (const float*)d_in[6 + br * 8 + 7];
        float* outv = (br == 0) ? ofp : ofc;

        cvt4<<<dim3(576, 4), dim3(256), 0, stream>>>(Wq, Wk, W0, W1, Wb);

        // Q = x@Wq^T + bq ; K = x@Wk^T + bk   [M=16384,N=768,K=768]
        gemm_bt<0><<<dim3(6, 128, 1), dim3(256), 0, stream>>>(
            xbf, Wb, Qb, nullptr, Dn, Dn, Dn, Dn,
            0, 0, 0, 0, 0, 0, 0, 1.0f, bq, nullptr, nullptr);
        gemm_bt<0><<<dim3(6, 128, 1), dim3(256), 0, stream>>>(
            xbf, Wb + DD, Kb, nullptr, Dn, Dn, Dn, Dn,
            0, 0, 0, 0, 0, 0, 0, 1.0f, bk, nullptr, nullptr);

        // scores (bf16) + softmax-mean over heads -> adjb, denom
        for (int gg = 0; gg < ngrp; ++gg) {
            int hbase = gg * G;
            gemm_bt<0><<<dim3(4, 4, Bn * G), dim3(256), 0, stream>>>(
                Qb + hbase * DKn, Kb + hbase * DKn, SC, nullptr,
                Dn, Dn, Sn, DKn,
                (long)Sn * Dn, DKn, (long)Sn * Dn, DKn,
                (long)G * Sn * Sn, (long)Sn * Sn, lgG,
                sal, nullptr, nullptr, nullptr);
            softmax_multi<<<dim3(Bn * Sn / 4), dim3(256), 0, stream>>>(
                SC, adjf, adjb, denom, src_msk, G, gg == 0, gg == ngrp - 1);
        }

        // XW0T = W0 @ x^T   [M=768,N=512,K=768] batched over b
        gemm_bt<0><<<dim3(4, 6, Bn), dim3(256), 0, stream>>>(
            Wb + 2 * DD, xbf, XT, nullptr, Dn, Dn, Sn, Dn,
            0, 0, (long)Sn * Dn, 0, (long)Dn * Sn, 0, 0,
            1.0f, nullptr, nullptr, nullptr);

        // H1 = relu((adj @ XW0 + b0)/denom)   [M=512,N=768,K=512]
        gemm_bt<1><<<dim3(6, 4, Bn), dim3(256), 0, stream>>>(
            adjb, XT, Qb, nullptr, Sn, Sn, Dn, Sn,
            (long)Sn * Sn, 0, (long)Dn * Sn, 0, (long)Sn * Dn, 0, 0,
            1.0f, b0, denom, nullptr);

        // H1W1T = W1 @ H1^T   [M=768,N=512,K=768]
        gemm_bt<0><<<dim3(4, 6, Bn), dim3(256), 0, stream>>>(
            Wb + 3 * DD, Qb, XT, nullptr, Dn, Dn, Sn, Dn,
            0, 0, (long)Sn * Dn, 0, (long)Dn * Sn, 0, 0,
            1.0f, nullptr, nullptr, nullptr);

        // H2 fused: outv[b,n] += sum_m w(m)*relu((adj@H1W1 + b1)/denom)
        gemm_bt<2><<<dim3(6, 4, Bn), dim3(256), 0, stream>>>(
            adjb, XT, nullptr, outv, Sn, Sn, 0, Sn,
            (long)Sn * Sn, 0, (long)Dn * Sn, 0, 0, 0, 0,
            1.0f, b1, denom, (br == 1) ? aspect : nullptr);
    }

    final_kernel<<<dim3(Bn), dim3(256), 0, stream>>>(
        ofp, ofc, aspect, pooled,
        (const float*)d_in[22], (const float*)d_in[23],
        (const float*)d_in[24], (const float*)d_in[25], out);
}